// Round 4
// baseline (425.533 us; speedup 1.0000x reference)
//
#include <hip/hip_runtime.h>
#include <stdint.h>
#include <stddef.h>

// ---------------------------------------------------------------------------
// BayesianDTW forward on MI355X — R10.
// Base: R9 (passed, 343us dispatch, absmax 8.0; R3-proven log2-domain math).
// Changes (structure only, math untouched):
//   1. Per-step DIRECT global store of (uA,uB)*ln2 — lds_o ring, per-step
//      ds_write, boundary 32-read flush, and separate edge-dup all DELETED.
//      (The R7 "edge dup" address (s+1)*SW is the same cell as flush col
//      s*SW+128.) Lane 63 additionally issues an agent-scope st_edge to its
//      second output cell for cross-XCD visibility (plain stores are not
//      XCD-coherent; same value -> benign race).
//   2. Flag published ONE CHUNK EARLIER: chunk f=m-4's last edge store is
//      issued at t=16m+14 (second-to-last step), so boundary vmcnt(1)
//      (leaves only the t=16m+15 store outstanding) proves chunk m-4
//      drained BY COUNTING -> publish flag m-3 (R7: m-4). Per-hop lag
//      8 -> 7 chunks (makespan -112 steps).
//   3. W-ring prefetch lead 2 -> 3 steps (ring lifetime: chunk q written
//      at boundary q-2, first read t=16q-3: 14-step margin; overwrite vs
//      last-read margin 51 steps).
// ---------------------------------------------------------------------------

#define NBATCH  32
#define NA      512
#define NB      1024
#define NSTRIPE 8
#define SW      128          // cols per stripe
#define CH      16           // rows per chunk
#define NCHUNK  (NA / CH)    // 32
#define LSTR    128          // LDS row stride (floats)
#define OROWS   513
#define OCOLS   1025
#define FSTRIDE 32           // flag padding: 128 B

#define NEGV    (-1e20f)
#define LOG2E   (1.4426950408889634f)
#define LN2     (0.6931471805599453f)
#define NEG2    (-1.4426950408889634e20f)   // NEGV in log2 units
#define FLAGTAG 0x5A000000u

#define EXP2F(x) __builtin_amdgcn_exp2f(x)   // v_exp_f32: 2^x
#define LOG2F(x) __builtin_amdgcn_logf(x)    // v_log_f32: log2(x)

__device__ __forceinline__ float lse3_2(float a, float b, float c) {
    // log2(2^a + 2^b + 2^c); inputs/outputs in log2 units. NaN-free for
    // finite inputs (diffs <= 0, exp2 in [0,1], sum in [1,3]).
    float m = fmaxf(fmaxf(a, b), c);           // v_max3_f32
    float s = EXP2F(a - m) + EXP2F(b - m) + EXP2F(c - m);
    return m + LOG2F(s);
}

__device__ __forceinline__ float rdlane(float v, int l) {
    return __int_as_float(__builtin_amdgcn_readlane(__float_as_int(v), l));
}

// lane i <- lane i-1 across the full wave, pure VALU:
// DPP row_shr:1 (16-lane rows) + readlane patches at lanes 16/32/48.
// Lane 0 result unused (edge path).
__device__ __forceinline__ float lane_shr1(float x, int lane) {
    int xi  = __float_as_int(x);
    int shr = __builtin_amdgcn_update_dpp(0, xi, 0x111, 0xf, 0xf, true);
    float v = __int_as_float(shr);
    float a15 = rdlane(x, 15), a31 = rdlane(x, 31), a47 = rdlane(x, 47);
    v = (lane == 16) ? a15 : v;
    v = (lane == 32) ? a31 : v;
    v = (lane == 48) ? a47 : v;
    return v;
}

__device__ __forceinline__ unsigned int ld_flag(unsigned int* fp) {
    return __hip_atomic_load(fp, __ATOMIC_RELAXED, __HIP_MEMORY_SCOPE_AGENT);
}
__device__ __forceinline__ void st_flag(unsigned int* fp, unsigned int v) {
    __hip_atomic_store(fp, v, __ATOMIC_RELAXED, __HIP_MEMORY_SCOPE_AGENT);
}
__device__ __forceinline__ float ld_edge(const float* p) {
    return __hip_atomic_load((float*)p, __ATOMIC_RELAXED, __HIP_MEMORY_SCOPE_AGENT);
}
__device__ __forceinline__ void st_edge(float* p, float v) {
    __hip_atomic_store(p, v, __ATOMIC_RELAXED, __HIP_MEMORY_SCOPE_AGENT);
}

__device__ __forceinline__ void wait_flag(unsigned int* fp, unsigned int need) {
    for (int k = 0; k < (1 << 22); ++k) {
        unsigned int v = ld_flag(fp);
        if ((v >> 24) == 0x5Au && (v & 0x00FFFFFFu) >= need) break;
    }
    asm volatile("" ::: "memory");
}

__global__ __launch_bounds__(64, 1)
void dtw_pipe(const float* __restrict__ W, float* __restrict__ out,
              unsigned int* __restrict__ flags)
{
    __shared__ float lds_w[128 * LSTR];   // W ring: row r at slot r&127

    const int lane = (int)threadIdx.x;
    const int bid  = (int)blockIdx.x;             // s*32 + b
    const int b    = bid & (NBATCH - 1);
    const int s    = bid >> 5;

    const float*  Wb  = W + ((size_t)b * NA) * NB + s * SW;
    float*        ob  = out + (size_t)b * OROWS * OCOLS;
    unsigned int* fmy = flags + (size_t)bid * FSTRIDE;
    unsigned int* fup = flags + (size_t)(bid - NBATCH) * FSTRIDE;

    // ---- zero W-ring slots 48..127 (read-before-stage region) ----
    {
        float4 z4 = make_float4(0.f, 0.f, 0.f, 0.f);
        float4* dst = (float4*)&lds_w[48 * LSTR];
        for (int i = lane; i < (80 * LSTR) / 4; i += 64) dst[i] = z4;
    }

    // ---- boundary cells of output (final values; nobody reads these) ----
    ob[s * SW + 1 + lane]      = NEGV;
    ob[s * SW + 1 + 64 + lane] = NEGV;
    if (s == 0) {
        if (lane == 0) ob[0] = 0.0f;
        for (int r = lane; r < NA; r += 64)
            ob[(size_t)(r + 1) * OCOLS] = NEGV;
    }

    // ---- reg-staged W prologue: chunks 0,1 -> LDS; chunk 2 loads in flight
    float2 wst[CH];      // staged chunk in flight (32 VGPR)
    float2 wst1[CH];     // prologue only
    #pragma unroll
    for (int rr = 0; rr < CH; ++rr)
        wst[rr]  = *(const float2*)(Wb + (size_t)rr * NB + 2 * lane);
    #pragma unroll
    for (int rr = 0; rr < CH; ++rr)
        wst1[rr] = *(const float2*)(Wb + (size_t)(CH + rr) * NB + 2 * lane);

    // ---- edge prefetch (log2 units; lanes 0..15 hold 16 rows each) ----
    float evcur = -1e30f, evnxt = -1e30f, lres = -1e30f;
    if (s > 0) {
        wait_flag(fup, 1u);
        if (lane < CH)
            evcur = ld_edge(&ob[(size_t)(1 + lane) * OCOLS + s * SW]) * LOG2E;
        wait_flag(fup, 2u);
        if (lane < CH)
            evnxt = ld_edge(&ob[(size_t)(CH + 1 + lane) * OCOLS + s * SW]) * LOG2E;
        wait_flag(fup, 3u);
        if (lane < CH)
            lres  = ld_edge(&ob[(size_t)(2 * CH + 1 + lane) * OCOLS + s * SW]) * LOG2E;
    }

    asm volatile("s_waitcnt vmcnt(0)" ::: "memory");   // loads + edges done

    // chunks 0,1 -> ring slots 0..31
    #pragma unroll
    for (int rr = 0; rr < CH; ++rr)
        *(float2*)&lds_w[rr * LSTR + 2 * lane] = wst[rr];
    #pragma unroll
    for (int rr = 0; rr < CH; ++rr)
        *(float2*)&lds_w[(CH + rr) * LSTR + 2 * lane] = wst1[rr];
    // issue chunk-2 loads (consumed: ds_write at boundary m=0)
    #pragma unroll
    for (int rr = 0; rr < CH; ++rr)
        wst[rr] = *(const float2*)(Wb + (size_t)(2 * CH + rr) * NB + 2 * lane);

    // ---- systolic state (log2 units, R3-proven — VERBATIM R7/R9) ----
    float topA = NEG2, topB = NEG2;   // mu[i-1, jA], mu[i-1, jB] (log2)
    float sh_in = NEG2;               // left neighbor's uB from prev step
    float tl_reg = NEG2;              // mu[i-1, jA-1]
    float ev_im1 = (s == 0) ? 0.0f : NEG2;  // lane0 topleft: mu[0,128s]·log2e
    unsigned int fpoll = 0;

    // W prefetch: w_cur = row r(t), +1, +2; issue +3 each step
    float2 w_cur = *(const float2*)&lds_w[((0 - lane) & 127) * LSTR + 2 * lane];
    float2 w_nx1 = *(const float2*)&lds_w[((1 - lane) & 127) * LSTR + 2 * lane];
    float2 w_nx2 = *(const float2*)&lds_w[((2 - lane) & 127) * LSTR + 2 * lane];

    // per-step direct output store: obase + ooff = &ob[(r+1)*OCOLS + col0]
    float* obase = ob + s * SW + 1 + 2 * lane;
    int    ooff  = (1 - lane) * OCOLS;      // row r+1 for r = -lane (t=0)

    auto step = [&](int m_, int tt) {
        const int t = (m_ << 4) + tt;
        const int r = t - lane;
        if (tt == 1 && s > 0) fpoll = ld_flag(fup);      // hidden poll
        // prefetch W row r+3 (3-step lead > ds latency)
        float2 w_pre = *(const float2*)&lds_w[((r + 3) & 127) * LSTR + 2 * lane];
        // edge broadcast: wave-uniform immediate lane index -> v_readlane
        const float ev_i = rdlane(evcur, tt);
        // ---- carried chain ----
        const float lf = (lane == 0) ? ev_i   : sh_in;   // mu[i, jA-1]
        const float tl = (lane == 0) ? ev_im1 : tl_reg;  // mu[i-1, jA-1]
        const float uA = fmaf(w_cur.x, LOG2E, lse3_2(topA, lf, tl));
        const float uB = fmaf(w_cur.y, LOG2E, lse3_2(topB, uA, topA));
        const bool on = (r >= 0);
        if (on & (r < NA)) {                             // direct global store
            float* op = obase + (ptrdiff_t)ooff;
            *(float2*)op = make_float2(uA * LN2, uB * LN2);
            // lane 63's col jB = (s+1)*SW: agent-scope dup for cross-XCD
            // visibility of the edge column (same value, same address as
            // the float2's 2nd element -> benign).
            if ((s < NSTRIPE - 1) & (lane == 63))
                st_edge(op + 1, uB * LN2);
        }
        topA   = on ? uA : NEG2;
        topB   = on ? uB : NEG2;
        tl_reg = on ? lf : NEG2;
        ev_im1 = ev_i;
        sh_in  = lane_shr1(uB, lane);                    // pure-VALU pass
        w_cur = w_nx1; w_nx1 = w_nx2; w_nx2 = w_pre;
        ooff += OCOLS;
    };

    for (int m = 0; m < 35; ++m) {
        #pragma unroll
        for (int tt = 0; tt < 16; ++tt) step(m, tt);

        // ================= chunk boundary (t = 16m+15 done) =================
        // 1) vmcnt(1): leaves at most the newest vmem op (last step's store,
        //    chunk m-3 rows) outstanding. Chunk f=m-4's last edge store was
        //    issued at t=16m+14 -> provably drained BY COUNTING. Also drains
        //    the staging loads issued at boundary m-1.
        asm volatile("s_waitcnt vmcnt(1)" ::: "memory");
        // 2) publish flag p=m-3 (claims chunks <= m-4 visible)
        {
            const int p = m - 3;
            if (s < NSTRIPE - 1 && p >= 1 && lane == 0)
                st_flag(fmy, FLAGTAG + (unsigned)p);
        }
        // 3) ds_write staged chunk cw=m+2 into the ring (first read at
        //    t=16(m+2)-3; overwritten rows' last read was t=16m-36 < now).
        {
            const int cw = m + 2;
            if (cw < NCHUNK) {
                #pragma unroll
                for (int rr = 0; rr < CH; ++rr) {
                    const int slot = ((cw << 4) + rr) & 127;
                    *(float2*)&lds_w[slot * LSTR + 2 * lane] = wst[rr];
                }
            }
        }
        // 4) rotate edge regs; load chunk m+3 edges (need m+4, polled tt==1)
        evcur = evnxt; evnxt = lres;
        const int c = m + 3;
        if (s > 0 && c < NCHUNK) {
            const unsigned need = (unsigned)(m + 4);
            if (!((fpoll >> 24) == 0x5Au && (fpoll & 0x00FFFFFFu) >= need))
                wait_flag(fup, need);
            lres = -1e30f;
            if (lane < CH)
                lres = ld_edge(&ob[(size_t)((c << 4) + 1 + lane) * OCOLS + s * SW])
                       * LOG2E;
        }
        // 5) issue staging LOADS for chunk c = m+3 (ds_write at boundary m+1)
        if (c < NCHUNK) {
            const float* wsrc = Wb + (size_t)(c << 4) * NB;
            #pragma unroll
            for (int rr = 0; rr < CH; ++rr)
                wst[rr] = *(const float2*)(wsrc + (size_t)rr * NB + 2 * lane);
        }
    }

    // tail steps t = 560..574 (lane 63 finishes row 511 at t=574)
    #pragma unroll
    for (int tt = 0; tt < 15; ++tt) step(35, tt);

    // ---- epilogue: all stores drained, publish final flag ----
    asm volatile("s_waitcnt vmcnt(0)" ::: "memory");
    if (s < NSTRIPE - 1 && lane == 0)
        st_flag(fmy, FLAGTAG + (unsigned)NCHUNK);     // claims chunks <= 31
}

extern "C" void kernel_launch(void* const* d_in, const int* in_sizes, int n_in,
                              void* d_out, int out_size, void* d_ws, size_t ws_size,
                              hipStream_t stream) {
    const float*  W     = (const float*)d_in[0];
    float*        out   = (float*)d_out;
    unsigned int* flags = (unsigned int*)d_ws;
    (void)in_sizes; (void)n_in; (void)out_size; (void)ws_size;
    hipLaunchKernelGGL(dtw_pipe, dim3(NBATCH * NSTRIPE), dim3(64), 0, stream,
                       W, out, flags);
}

// Round 5
// 417.730 us; speedup vs baseline: 1.0187x; 1.0187x over previous
//
#include <hip/hip_runtime.h>
#include <stdint.h>
#include <stddef.h>

// ---------------------------------------------------------------------------
// BayesianDTW forward on MI355X — R11.
// Base: R9 (passed, 343us dispatch, absmax 8.0; R3-proven log2 lse3 math).
// Model from R9/R10 nulls: step rate (~560cy) is single-wave in-order ISSUE
// bound (~50 instr/step x ~10cy dependent latency), not chain latency, not
// memory-path structure. R11 attacks instruction count + lag margins:
//   1. W via per-lane GLOBAL loads -> 4-deep register ring. Deletes lds_w,
//      per-step ds_read+addr, 32-op boundary staging. W lines are L1-hot
//      (each 128B line feeds 16 lanes over 16 steps). Boundary waitcnt
//      vmcnt(1)->vmcnt(4): in-order vmcnt retirement => <=4 outstanding =
//      {3 newest W loads + this boundary's dup} => prev dup drained.
//   2. CH 16->8: dup f=m-8 at boundary m; publish v=f (claims <=f-1,
//      proven by vmcnt draining dup f-1 from boundary m-1); consumer at
//      boundary m loads chunk c=m+3, needs v=m+4 => upstream boundary
//      m+12 => lag 96 steps/hop (was 128). Makespan 1471->1247 steps.
//   3. Loop split: prologue m0-7 (r>=0 gates), middle m8-63 (all lanes
//      active, NO gating), epilogue m64-70 + 7-step tail (r<NA guard).
//   4. lse3: max term's exp2 == 1 => 1 + exp2(med3-m) + exp2(min3-m)
//      (2 transcendentals instead of 3; bit-equivalent class).
// Protocol otherwise R9-verbatim (hidden fpoll at tt==1, 3-deep edge
// prefetch, agent-scope edge dup/loads, wait_flag fallback).
// ---------------------------------------------------------------------------

#define NBATCH  32
#define NA      512
#define NB      1024
#define NSTRIPE 8
#define SW      128          // cols per stripe
#define CH      8            // rows per chunk (R11: was 16)
#define NCHUNK  (NA / CH)    // 64
#define LSTR    128          // lds_o row stride (floats)
#define OROWS   513
#define OCOLS   1025
#define FSTRIDE 32           // flag padding: 128 B

#define NEGV    (-1e20f)
#define LOG2E   (1.4426950408889634f)
#define LN2     (0.6931471805599453f)
#define NEG2    (-1.4426950408889634e20f)   // NEGV in log2 units
#define FLAGTAG 0x5A000000u

#define EXP2F(x) __builtin_amdgcn_exp2f(x)   // v_exp_f32: 2^x
#define LOG2F(x) __builtin_amdgcn_logf(x)    // v_log_f32: log2(x)

__device__ __forceinline__ float lse3_2(float a, float b, float c) {
    // log2(2^a + 2^b + 2^c), log2 units. exp2 of the max is exactly 1 ->
    // only 2 transcendentals. NaN-free for finite inputs (diffs <= 0).
    float m  = fmaxf(fmaxf(a, b), c);                  // v_max3_f32
    float md = __builtin_amdgcn_fmed3f(a, b, c);       // v_med3_f32
    float mn = fminf(fminf(a, b), c);                  // v_min3_f32
    float ss = 1.0f + EXP2F(md - m) + EXP2F(mn - m);
    return m + LOG2F(ss);
}

__device__ __forceinline__ float rdlane(float v, int l) {
    return __int_as_float(__builtin_amdgcn_readlane(__float_as_int(v), l));
}

// lane i <- lane i-1 across the full wave, pure VALU:
// DPP row_shr:1 (16-lane rows) + readlane patches at lanes 16/32/48.
// Lane 0 result unused (edge path).
__device__ __forceinline__ float lane_shr1(float x, int lane) {
    int xi  = __float_as_int(x);
    int shr = __builtin_amdgcn_update_dpp(0, xi, 0x111, 0xf, 0xf, true);
    float v = __int_as_float(shr);
    float a15 = rdlane(x, 15), a31 = rdlane(x, 31), a47 = rdlane(x, 47);
    v = (lane == 16) ? a15 : v;
    v = (lane == 32) ? a31 : v;
    v = (lane == 48) ? a47 : v;
    return v;
}

__device__ __forceinline__ unsigned int ld_flag(unsigned int* fp) {
    return __hip_atomic_load(fp, __ATOMIC_RELAXED, __HIP_MEMORY_SCOPE_AGENT);
}
__device__ __forceinline__ void st_flag(unsigned int* fp, unsigned int v) {
    __hip_atomic_store(fp, v, __ATOMIC_RELAXED, __HIP_MEMORY_SCOPE_AGENT);
}
__device__ __forceinline__ float ld_edge(const float* p) {
    return __hip_atomic_load((float*)p, __ATOMIC_RELAXED, __HIP_MEMORY_SCOPE_AGENT);
}
__device__ __forceinline__ void st_edge(float* p, float v) {
    __hip_atomic_store(p, v, __ATOMIC_RELAXED, __HIP_MEMORY_SCOPE_AGENT);
}

__device__ __forceinline__ void wait_flag(unsigned int* fp, unsigned int need) {
    for (int k = 0; k < (1 << 22); ++k) {
        unsigned int v = ld_flag(fp);
        if ((v >> 24) == 0x5Au && (v & 0x00FFFFFFu) >= need) break;
    }
    asm volatile("" ::: "memory");
}

__global__ __launch_bounds__(64, 1)
void dtw_pipe(const float* __restrict__ W, float* __restrict__ out,
              unsigned int* __restrict__ flags)
{
    __shared__ float lds_o[128 * LSTR];   // output ring (ln units, final)

    const int lane = (int)threadIdx.x;
    const int bid  = (int)blockIdx.x;             // s*32 + b
    const int b    = bid & (NBATCH - 1);
    const int s    = bid >> 5;

    const float*  Wb  = W + ((size_t)b * NA) * NB + s * SW;
    float*        ob  = out + (size_t)b * OROWS * OCOLS;
    unsigned int* fmy = flags + (size_t)bid * FSTRIDE;
    unsigned int* fup = flags + (size_t)(bid - NBATCH) * FSTRIDE;

    // ---- boundary cells of output (final values; nobody reads these) ----
    ob[s * SW + 1 + lane]      = NEGV;
    ob[s * SW + 1 + 64 + lane] = NEGV;
    if (s == 0) {
        if (lane == 0) ob[0] = 0.0f;
        for (int r = lane; r < NA; r += 64)
            ob[(size_t)(r + 1) * OCOLS] = NEGV;
    }

    // ---- W register ring: prime rows 0..3 (clamped; r(t)=t-lane) ----
    float2 wr[4];
    #pragma unroll
    for (int k = 0; k < 4; ++k) {
        int rowc = k - lane;
        rowc = rowc < 0 ? 0 : rowc;
        wr[k] = *(const float2*)&Wb[(size_t)rowc * NB + 2 * lane];
    }

    // ---- edge prefetch (log2 units; lanes 0..7 hold 8 rows each) ----
    float evcur = -1e30f, evnxt = -1e30f, lres = -1e30f;
    if (s > 0) {
        wait_flag(fup, 1u);
        if (lane < CH)
            evcur = ld_edge(&ob[(size_t)(1 + lane) * OCOLS + s * SW]) * LOG2E;
        wait_flag(fup, 2u);
        if (lane < CH)
            evnxt = ld_edge(&ob[(size_t)(CH + 1 + lane) * OCOLS + s * SW]) * LOG2E;
        wait_flag(fup, 3u);
        if (lane < CH)
            lres  = ld_edge(&ob[(size_t)(2 * CH + 1 + lane) * OCOLS + s * SW]) * LOG2E;
    }

    asm volatile("s_waitcnt vmcnt(0)" ::: "memory");   // primes + edges done

    // ---- systolic state (log2 units, R3-proven) ----
    float topA = NEG2, topB = NEG2;   // mu[i-1, jA], mu[i-1, jB] (log2)
    float sh_in = NEG2;               // left neighbor's uB from prev step
    float tl_reg = NEG2;              // mu[i-1, jA-1]
    float ev_im1 = (s == 0) ? 0.0f : NEG2;  // lane0 topleft: mu[0,128s]·log2e
    unsigned int fpoll = 0;

    // step body. GATE: prologue r>=0 gating (R9-verbatim). GNA: epilogue
    // r<NA store guard. Middle: neither (provably all-active, t in [64,511]).
    auto stepc = [&](int m, int tt, bool GATE, bool GNA) {
        const int t = 8 * m + tt;
        const int r = t - lane;
        if (tt == 1 && s > 0) fpoll = ld_flag(fup);      // hidden poll
        const float2 wv = wr[tt & 3];                    // copy, then refill
        {   // issue W load for row r+4 into the same slot (WAR-safe: copy
            // above is issued first; load lands >=1 step later, consumed +4)
            int rowc = r + 4;
            rowc = rowc < 0 ? 0 : (rowc > NA - 1 ? NA - 1 : rowc);
            wr[tt & 3] = *(const float2*)&Wb[(size_t)rowc * NB + 2 * lane];
        }
        const float ev_i = rdlane(evcur, tt);
        // ---- carried chain (R3-proven) ----
        const float lf = (lane == 0) ? ev_i   : sh_in;   // mu[i, jA-1]
        const float tl = (lane == 0) ? ev_im1 : tl_reg;  // mu[i-1, jA-1]
        const float uA = fmaf(wv.x, LOG2E, lse3_2(topA, lf, tl));
        const float uB = fmaf(wv.y, LOG2E, lse3_2(topB, uA, topA));
        bool db = true;
        if (GATE) db = (r >= 0);
        if (GNA)  db = (r < NA);
        if (db) {                                        // off-chain store (ln)
            *(float2*)&lds_o[(r & 127) * LSTR + 2 * lane]
                = make_float2(uA * LN2, uB * LN2);
        }
        if (GATE) {
            const bool on = (r >= 0);
            topA   = on ? uA : NEG2;
            topB   = on ? uB : NEG2;
            tl_reg = on ? lf : NEG2;
        } else {
            topA = uA; topB = uB; tl_reg = lf;
        }
        ev_im1 = ev_i;
        sh_in  = lane_shr1(uB, lane);                    // pure-VALU pass
    };

    auto boundary = [&](int m) {
        const int f = m - 8;                  // chunk fully complete (skew 63)
        // 1) agent-scope edge-column dup for chunk f
        if (s < NSTRIPE - 1 && f >= 0 && lane < CH) {
            const int rw = (f << 3) + lane;
            const float evl = lds_o[(rw & 127) * LSTR + 127];
            st_edge(ob + (size_t)(rw + 1) * OCOLS + (s + 1) * SW, evl);
        }
        // 2) vmcnt(4): in-order retirement => everything except the 4
        //    newest vmem ops (3 W-ring loads + this dup) has retired, in
        //    particular dup(f-1) from boundary m-1 -> publish v=f
        //    (claims chunks <= f-1 visible).
        asm volatile("s_waitcnt vmcnt(4)" ::: "memory");
        if (s < NSTRIPE - 1 && f >= 1 && lane == 0)
            st_flag(fmy, FLAGTAG + (unsigned)f);
        // 3) coalesced flush of chunk f
        if (f >= 0) {
            #pragma unroll
            for (int rr = 0; rr < CH; ++rr) {
                const int rw = (f << 3) + rr;
                const float v0 = lds_o[(rw & 127) * LSTR + lane];
                const float v1 = lds_o[(rw & 127) * LSTR + 64 + lane];
                float* orow = ob + (size_t)(rw + 1) * OCOLS + s * SW + 1;
                orow[lane]      = v0;
                orow[64 + lane] = v1;
            }
        }
        // 4) rotate edge regs; load chunk m+3 (need m+4, polled at tt==1)
        evcur = evnxt; evnxt = lres;
        const int c = m + 3;
        if (s > 0 && c < NCHUNK) {
            const unsigned need = (unsigned)(m + 4);
            if (!((fpoll >> 24) == 0x5Au && (fpoll & 0x00FFFFFFu) >= need))
                wait_flag(fup, need);
            lres = -1e30f;
            if (lane < CH)
                lres = ld_edge(&ob[(size_t)((c << 3) + 1 + lane) * OCOLS + s * SW])
                       * LOG2E;
        }
    };

    // ---- prologue: m=0..7 (some lanes r<0; full R9 gating) ----
    for (int m = 0; m < 8; ++m) {
        #pragma unroll
        for (int tt = 0; tt < 8; ++tt) stepc(m, tt, true, false);
        boundary(m);
    }
    // ---- middle: m=8..63 (t in [64,511]: every lane 0<=r<NA; no gates) ----
    for (int m = 8; m < 64; ++m) {
        #pragma unroll
        for (int tt = 0; tt < 8; ++tt) stepc(m, tt, false, false);
        boundary(m);
    }
    // ---- epilogue: m=64..70 (lane0 side r>=NA; store guard only) ----
    for (int m = 64; m < 71; ++m) {
        #pragma unroll
        for (int tt = 0; tt < 8; ++tt) stepc(m, tt, false, true);
        boundary(m);
    }
    // tail steps t = 568..574 (lane 63 finishes row 511 at t=574)
    #pragma unroll
    for (int tt = 0; tt < 7; ++tt) stepc(71, tt, false, true);

    // ---- final: chunk 63 ----
    {
        const int f = NCHUNK - 1;
        if (s < NSTRIPE - 1 && lane < CH) {
            const int rw = (f << 3) + lane;
            const float evl = lds_o[(rw & 127) * LSTR + 127];
            st_edge(ob + (size_t)(rw + 1) * OCOLS + (s + 1) * SW, evl);
        }
        asm volatile("s_waitcnt vmcnt(1)" ::: "memory");
        if (s < NSTRIPE - 1 && lane == 0)
            st_flag(fmy, FLAGTAG + (unsigned)f);          // chunks <= 62
        #pragma unroll
        for (int rr = 0; rr < CH; ++rr) {
            const int rw = (f << 3) + rr;
            const float v0 = lds_o[(rw & 127) * LSTR + lane];
            const float v1 = lds_o[(rw & 127) * LSTR + 64 + lane];
            float* orow = ob + (size_t)(rw + 1) * OCOLS + s * SW + 1;
            orow[lane]      = v0;
            orow[64 + lane] = v1;
        }
        asm volatile("s_waitcnt vmcnt(0)" ::: "memory");
        if (s < NSTRIPE - 1 && lane == 0)
            st_flag(fmy, FLAGTAG + (unsigned)NCHUNK);     // all 64 chunks
    }
}

extern "C" void kernel_launch(void* const* d_in, const int* in_sizes, int n_in,
                              void* d_out, int out_size, void* d_ws, size_t ws_size,
                              hipStream_t stream) {
    const float*  W     = (const float*)d_in[0];
    float*        out   = (float*)d_out;
    unsigned int* flags = (unsigned int*)d_ws;
    (void)in_sizes; (void)n_in; (void)out_size; (void)ws_size;
    hipLaunchKernelGGL(dtw_pipe, dim3(NBATCH * NSTRIPE), dim3(64), 0, stream,
                       W, out, flags);
}